// Round 18
// baseline (270.440 us; speedup 1.0000x reference)
//
#include <hip/hip_runtime.h>
#include <hip/hip_bf16.h>
#include <stdint.h>

#define BB  1024
#define SS  20
#define DD  128
#define G3  384      // 3*D
#define NII 100000
#define KXX 136      // D + R
#define RPB 2        // gru rows per block
#define JPB 256      // gemm j-columns per block

typedef float         f32x4 __attribute__((ext_vector_type(4)));
typedef __bf16        bf16x8 __attribute__((ext_vector_type(8)));
typedef unsigned int  u32;
typedef unsigned int  u32x4 __attribute__((ext_vector_type(4)));

// acc += dot(f16x2(w), f16x2(h))  -- guaranteed packed dot2 on gfx950
#define DOT2(acc, w, h) \
  asm("v_dot2_f32_f16 %0, %1, %2, %0" : "+v"(acc) : "v"(w), "v"(h))

__device__ __forceinline__ u32 pk16(float a, float b) {
  auto p = __builtin_amdgcn_cvt_pkrtz(a, b);   // __fp16x2, same 32-bit layout
  return __builtin_bit_cast(u32, p);
}

__device__ __forceinline__ unsigned short f2bf(float x) {
  uint32_t u = __float_as_uint(x);
  uint32_t r = (u + 0x7fffu + ((u >> 16) & 1u)) >> 16;   // RNE
  return (unsigned short)r;
}

__device__ __forceinline__ float sigf(float x) { return 1.f / (1.f + expf(-x)); }

// ---------------- K_front: gx [0,2560) | zero_seg [2560,5120) | M [5120,5184)
//                  | Wh->f16 pack [5184,5280) ----------------
__global__ __launch_bounds__(256) void k_front(const int* __restrict__ items,
                                               const float* __restrict__ rew,
                                               const float* __restrict__ table,
                                               const float* __restrict__ Wx,
                                               const float* __restrict__ bx,
                                               const float* __restrict__ Wu,
                                               const float* __restrict__ Wi,
                                               const float* __restrict__ Wh,
                                               float* __restrict__ gx,
                                               float* __restrict__ sums,
                                               float* __restrict__ counts,
                                               float* __restrict__ M,
                                               u32* __restrict__ Whf16) {
  __shared__ float Wl[96][140];
  __shared__ float Al[32][128];
  __shared__ float rl[32];
  int bid = blockIdx.x;
  int t = threadIdx.x;
  if (bid < 2560) {
    // ---- gx: Mp=4 x Ng=3 tile ----
    int gt = bid & 3, pt = bid >> 2;
    int g0 = gt * 96, p0 = pt * 32;
    for (int i = t; i < 96 * 34; i += 256) {
      int r = i / 34, c = i % 34;
      f32x4 v = *(const f32x4*)(Wx + (size_t)(g0 + r) * KXX + c * 4);
      *(f32x4*)&Wl[r][c * 4] = v;
    }
    for (int i = t; i < 32 * 32; i += 256) {
      int r = i >> 5, c = i & 31;
      int it = items[p0 + r];
      *(f32x4*)&Al[r][c * 4] = *(const f32x4*)(table + (size_t)it * DD + c * 4);
    }
    if (t < 32) rl[t] = rew[p0 + t];
    __syncthreads();

    int tg = t & 31, pq = t >> 5;
    float acc[4][3] = {};
    for (int k4 = 0; k4 < 32; ++k4) {
      f32x4 a[4];
#pragma unroll
      for (int i = 0; i < 4; ++i) a[i] = *(f32x4*)&Al[pq + 8 * i][k4 * 4];
#pragma unroll
      for (int u = 0; u < 3; ++u) {
        f32x4 w = *(f32x4*)&Wl[tg + 32 * u][k4 * 4];
#pragma unroll
        for (int i = 0; i < 4; ++i)
          acc[i][u] += a[i].x * w.x + a[i].y * w.y + a[i].z * w.z + a[i].w * w.w;
      }
    }
#pragma unroll
    for (int u = 0; u < 3; ++u) {
      int gl = tg + 32 * u, g = g0 + gl;
      float wxr = 0.f;
#pragma unroll
      for (int q = 0; q < 8; ++q) wxr += Wl[gl][128 + q];
      float bxv = bx[g];
#pragma unroll
      for (int i = 0; i < 4; ++i) {
        int p = p0 + pq + 8 * i;
        gx[(size_t)p * G3 + g] = acc[i][u] + rl[pq + 8 * i] * wxr + bxv;
      }
    }
  } else if (bid < 5120) {
    // ---- zero touched sums/counts ----
    int id = (bid - 2560) * 256 + t;
    int p = id >> 5, c = id & 31;
    int it = items[p];
    f32x4 z = {0.f, 0.f, 0.f, 0.f};
    *(f32x4*)(sums + (size_t)it * DD + c * 4) = z;
    if (c == 0) counts[it] = 0.f;
  } else if (bid < 5184) {
    // ---- M = W_u @ W_i^T ----
    int idx = (bid - 5120) * 256 + t;
    int k1 = idx >> 7, k2 = idx & 127;
    float acc = 0.f;
    for (int e = 0; e < DD; ++e)
      acc = fmaf(Wu[k1 * DD + e], Wi[k2 * DD + e], acc);
    M[idx] = acc;
  } else {
    // ---- Wh -> packed f16 pairs ----
    int idx = (bid - 5184) * 256 + t;       // 24576 total
    int g = idx >> 6, c2 = idx & 63;
    const float* src = Wh + (size_t)g * DD + c2 * 2;
    Whf16[idx] = pk16(src[0], src[1]);
  }
}

// ---------------- K_gru: 2 rows/block, wreg from pre-packed Whf16.
//   Pair-local gates: thread pair (2g,2g+1) holds ALL THREE gate pre-activations
//   for h-element g after shfl_xor(1) -> no ghl staging, ONE barrier/step,
//   double-buffered packed-f16 h. LDS hist + deferred tail atomics. ----------
__global__ __launch_bounds__(256, 2) void k_gru(const float* __restrict__ gx,
                                                const u32* __restrict__ Whf16,
                                                const float* __restrict__ bh,
                                                const int* __restrict__ items,
                                                float* __restrict__ sums,
                                                float* __restrict__ counts,
                                                float* __restrict__ hT) {
  __shared__ u32   hlu[2][RPB][DD / 2];  // double-buffered h, packed f16 pairs
  __shared__ float hist[RPB][SS][DD];    // 20.5 KB
  __shared__ int   itl[RPB][SS];
  int t = threadIdx.x;
  int gbase = t >> 1, half = t & 1;      // element index, k-half

  // wreg: 3 slices x 32 packed pairs = 96 u32 VGPRs, contiguous 128 B loads
  u32 wreg[3][32];
#pragma unroll
  for (int tt = 0; tt < 3; ++tt) {
    const u32* src = Whf16 + (size_t)(tt * 128 + gbase) * (DD / 2) + half * 32;
#pragma unroll
    for (int q4 = 0; q4 < 8; ++q4)
      *(u32x4*)&wreg[tt][q4 * 4] = *(const u32x4*)(src + q4 * 4);
  }

  float bh3[3];
#pragma unroll
  for (int q = 0; q < 3; ++q) bh3[q] = bh[q * 128 + gbase];

  int b0 = blockIdx.x * RPB;
  if (t < RPB * SS) itl[t / SS][t % SS] = items[(b0 + t / SS) * SS + t % SS];
  if (t < RPB * (DD / 2)) hlu[0][t >> 6][t & 63] = 0u;
  const float* gxr0 = gx + (size_t)b0 * SS * G3;
  const float* gxr1 = gx + (size_t)(b0 + 1) * SS * G3;
  float hprev[RPB] = {0.f, 0.f};
  __syncthreads();

  int cur = 0;
  for (int s = 0; s < SS; ++s) {
    // hoist all 6 gx loads to step top; dot2 chain hides their latency
    float gv[RPB][3];
#pragma unroll
    for (int q = 0; q < 3; ++q) {
      gv[0][q] = gxr0[s * G3 + q * 128 + gbase];
      gv[1][q] = gxr1[s * G3 + q * 128 + gbase];
    }
#pragma unroll
    for (int r = 0; r < RPB; ++r) {
      float a0 = 0.f, a1 = 0.f, a2 = 0.f;
#pragma unroll
      for (int q4 = 0; q4 < 8; ++q4) {
        u32x4 hv = *(u32x4*)&hlu[cur][r][half * 32 + q4 * 4];
#pragma unroll
        for (int e = 0; e < 4; ++e) {
          u32 h2 = hv[e];
          int j = q4 * 4 + e;
          DOT2(a0, wreg[0][j], h2);
          DOT2(a1, wreg[1][j], h2);
          DOT2(a2, wreg[2][j], h2);
        }
      }
      a0 += __shfl_xor(a0, 1);
      a1 += __shfl_xor(a1, 1);
      a2 += __shfl_xor(a2, 1);
      // pair-local gates for h[r][gbase]
      float rr = sigf(gv[r][0] + a0 + bh3[0]);
      float zz = sigf(gv[r][1] + a1 + bh3[1]);
      float nn = tanhf(gv[r][2] + rr * (a2 + bh3[2]));
      hprev[r] = (1.f - zz) * nn + zz * hprev[r];
      if (!half) {
        ((_Float16*)&hlu[cur ^ 1][r][0])[gbase] = (_Float16)hprev[r];
        hist[r][s][gbase] = hprev[r];
      }
    }
    cur ^= 1;
    __syncthreads();   // single barrier/step (WAR removed by double buffer)
  }
  if (!half) {
#pragma unroll
    for (int r = 0; r < RPB; ++r) hT[(b0 + r) * DD + gbase] = hprev[r];
  }
  // deferred segment atomics, single drain at exit
  for (int idx = t; idx < RPB * SS * DD; idx += 256) {
    int r = idx / (SS * DD), rem = idx % (SS * DD);
    int s = rem / DD, d = rem % DD;
    atomicAdd(sums + (size_t)itl[r][s] * DD + d, hist[r][s][d]);
  }
  if (t < RPB * SS) atomicAdd(counts + itl[t / SS][t % SS], 1.f);
}

// ---------------- K_back: items [0,12500) | uprime [12500,12564) ----------------
__global__ __launch_bounds__(256) void k_back(const float* __restrict__ table,
                                              const float* __restrict__ mem,
                                              const float* __restrict__ sums,
                                              const float* __restrict__ counts,
                                              unsigned short* __restrict__ Ibf,
                                              const int* __restrict__ ids,
                                              const float* __restrict__ hT,
                                              const float* __restrict__ M,
                                              unsigned short* __restrict__ Ubf) {
  __shared__ int   idsl[BB];
  __shared__ int   repl[16][16];
  __shared__ float hTl[16][DD];
  int bid = blockIdx.x;
  int t = threadIdx.x;
  if (bid < 12500) {
    size_t tid = (size_t)bid * 256 + t;
    size_t i = tid >> 5; int c = (int)(tid & 31);
    if (i >= NII) return;
    float cnt = counts[i];
    size_t base = i * DD + c * 4;
    f32x4 m  = *(const f32x4*)(mem + base);
    f32x4 tb = *(const f32x4*)(table + base);
    float vx, vy, vz, vw;
    if (cnt > 0.f) {
      f32x4 sm = *(const f32x4*)(sums + base);
      vx = 0.5f * (m.x + sm.x / cnt) + tb.x;
      vy = 0.5f * (m.y + sm.y / cnt) + tb.y;
      vz = 0.5f * (m.z + sm.z / cnt) + tb.z;
      vw = 0.5f * (m.w + sm.w / cnt) + tb.w;
    } else {
      vx = m.x + tb.x; vy = m.y + tb.y; vz = m.z + tb.z; vw = m.w + tb.w;
    }
    unsigned long long pack = (unsigned long long)f2bf(vx)
                            | ((unsigned long long)f2bf(vy) << 16)
                            | ((unsigned long long)f2bf(vz) << 32)
                            | ((unsigned long long)f2bf(vw) << 48);
    *(unsigned long long*)(Ibf + base) = pack;
  } else {
    int ub = bid - 12500;
    for (int i = t; i < BB; i += 256) idsl[i] = ids[i];
    __syncthreads();
    int b0 = ub * 16;
    int p = t >> 4, c = t & 15;
    int myid = idsl[b0 + p];
    int best = -1;
    for (int j = c * 64; j < c * 64 + 64; ++j)
      if (idsl[j] == myid) best = j;
    repl[p][c] = best;
    __syncthreads();
    if (c == 0) {
      int rr = -1;
#pragma unroll
      for (int q = 0; q < 16; ++q) rr = max(rr, repl[p][q]);
      repl[p][0] = rr;
    }
    __syncthreads();
    for (int i = t; i < 16 * 32; i += 256) {
      int rr = i >> 5, c4 = i & 31;
      int src = repl[rr][0];
      *(f32x4*)&hTl[rr][c4 * 4] = *(const f32x4*)(hT + (size_t)src * DD + c4 * 4);
    }
    __syncthreads();
    float acc[8] = {0.f, 0.f, 0.f, 0.f, 0.f, 0.f, 0.f, 0.f};
    for (int k1 = 0; k1 < DD; ++k1) {
      float hv = hTl[p][k1];
#pragma unroll
      for (int u = 0; u < 8; ++u)
        acc[u] = fmaf(hv, M[k1 * DD + c + 16 * u], acc[u]);
    }
#pragma unroll
    for (int u = 0; u < 8; ++u)
      Ubf[(size_t)(b0 + p) * DD + c + 16 * u] = f2bf(acc[u]);
  }
}

// ---------------- K_gemm: swapped MFMA, 256-wide j tile, LDS-staged epilogue
//   (one wave stores one ROW = 1024 B contiguous burst) -- round-10 WIN kernel ----
__device__ __forceinline__ bf16x8 bzero8() {
  bf16x8 z;
#pragma unroll
  for (int e = 0; e < 8; ++e) z[e] = (__bf16)0.f;
  return z;
}

__global__ __launch_bounds__(256, 2) void k_gemm(const unsigned short* __restrict__ Ubf,
                                                 const unsigned short* __restrict__ Ibf,
                                                 float* __restrict__ out) {
  __shared__ float ldsT[64][JPB + 4];   // pad 4: +1 bank rotation per b-row
  int j0 = blockIdx.x * JPB;
  int t = threadIdx.x;
  int wv = t >> 6, l = t & 63;
  int jw = j0 + wv * 64;                // wave owns a 64-wide j window
  int lr = l & 15, lk = l >> 4;

  bf16x8 afrag[4][4];
#pragma unroll
  for (int ji = 0; ji < 4; ++ji) {
    int ja = jw + ji * 16 + lr;
#pragma unroll
    for (int kk = 0; kk < 4; ++kk) {
      int k0 = kk * 32 + lk * 8;
      afrag[ji][kk] = (ja < NII) ? *(const bf16x8*)(Ibf + (size_t)ja * DD + k0) : bzero8();
    }
  }
  int jcl = l * 4;
  bool svalid = (j0 + jcl + 4 <= NII);   // NII % 4 == 0

  for (int bc = 0; bc < 16; ++bc) {
    int bw = bc * 64;
    f32x4 acc[4][4];                     // [ji][bi]
#pragma unroll
    for (int ji = 0; ji < 4; ++ji)
#pragma unroll
      for (int bi = 0; bi < 4; ++bi) { f32x4 z = {0.f,0.f,0.f,0.f}; acc[ji][bi] = z; }

#pragma unroll
    for (int kk = 0; kk < 4; ++kk) {
      int k0 = kk * 32 + lk * 8;
#pragma unroll
      for (int bi = 0; bi < 4; ++bi) {
        bf16x8 bfr = *(const bf16x8*)(Ubf + (size_t)(bw + bi * 16 + lr) * DD + k0);
#pragma unroll
        for (int ji = 0; ji < 4; ++ji)
          acc[ji][bi] = __builtin_amdgcn_mfma_f32_16x16x32_bf16(afrag[ji][kk], bfr,
                                                                acc[ji][bi], 0, 0, 0);
      }
    }
    __syncthreads();
#pragma unroll
    for (int ji = 0; ji < 4; ++ji) {
      int jl = wv * 64 + ji * 16 + lk * 4;
#pragma unroll
      for (int bi = 0; bi < 4; ++bi)
        *(f32x4*)&ldsT[bi * 16 + lr][jl] = acc[ji][bi];
    }
    __syncthreads();
    if (svalid) {
#pragma unroll
      for (int rr = 0; rr < 16; ++rr) {
        int row = rr * 4 + wv;
        f32x4 v = *(f32x4*)&ldsT[row][jcl];
        *(f32x4*)(out + (size_t)(bw + row) * NII + j0 + jcl) = v;
      }
    }
  }
}

extern "C" void kernel_launch(void* const* d_in, const int* in_sizes, int n_in,
                              void* d_out, int out_size, void* d_ws, size_t ws_size,
                              hipStream_t stream) {
  const int*   users_ids   = (const int*)  d_in[0];
  const int*   users_items = (const int*)  d_in[1];
  const float* users_rew   = (const float*)d_in[2];
  const float* items_table = (const float*)d_in[4];
  const float* items_mem   = (const float*)d_in[6];
  const float* Wx  = (const float*)d_in[7];
  const float* Wh  = (const float*)d_in[8];
  const float* bx  = (const float*)d_in[9];
  const float* bh  = (const float*)d_in[10];
  const float* W_u = (const float*)d_in[11];
  const float* W_i = (const float*)d_in[12];
  float* out = (float*)d_out;
  (void)in_sizes; (void)n_in; (void)out_size; (void)ws_size;

  char* ws = (char*)d_ws;
  size_t off = 0;
  auto alloc = [&](size_t bytes) {
    void* p = ws + off;
    off = (off + bytes + 255) & ~(size_t)255;
    return p;
  };
  float* sums   = (float*)alloc(sizeof(float) * (size_t)NII * DD);
  float* counts = (float*)alloc(sizeof(float) * NII);
  float* gx     = (float*)alloc(sizeof(float) * (size_t)BB * SS * G3);
  float* M      = (float*)alloc(sizeof(float) * DD * DD);
  float* hT     = (float*)alloc(sizeof(float) * BB * DD);
  u32*   Whf16  = (u32*)alloc(sizeof(u32) * G3 * (DD / 2));
  unsigned short* Ubf = (unsigned short*)alloc(sizeof(unsigned short) * BB * DD);
  unsigned short* Ibf = (unsigned short*)alloc(sizeof(unsigned short) * (size_t)NII * DD);

  hipLaunchKernelGGL(k_front, dim3(5280), dim3(256), 0, stream,
                     users_items, users_rew, items_table, Wx, bx, W_u, W_i, Wh,
                     gx, sums, counts, M, Whf16);
  hipLaunchKernelGGL(k_gru, dim3(BB / RPB), dim3(256), 0, stream,
                     gx, Whf16, bh, users_items, sums, counts, hT);
  hipLaunchKernelGGL(k_back, dim3(12564), dim3(256), 0, stream,
                     items_table, items_mem, sums, counts, Ibf,
                     users_ids, hT, M, Ubf);
  hipLaunchKernelGGL(k_gemm, dim3((NII + JPB - 1) / JPB), dim3(256), 0, stream,
                     Ubf, Ibf, out);
}

// Round 19
// 265.917 us; speedup vs baseline: 1.0170x; 1.0170x over previous
//
#include <hip/hip_runtime.h>
#include <hip/hip_bf16.h>
#include <stdint.h>

#define BB  1024
#define SS  20
#define DD  128
#define G3  384      // 3*D
#define NII 100000
#define KXX 136      // D + R
#define RPB 2        // gru rows per block
#define JPB 256      // gemm j-columns per block

typedef float         f32x4 __attribute__((ext_vector_type(4)));
typedef __bf16        bf16x8 __attribute__((ext_vector_type(8)));
typedef unsigned int  u32;
typedef unsigned int  u32x4 __attribute__((ext_vector_type(4)));

// acc += dot(f16x2(w), f16x2(h))  -- guaranteed packed dot2 on gfx950
#define DOT2(acc, w, h) \
  asm("v_dot2_f32_f16 %0, %1, %2, %0" : "+v"(acc) : "v"(w), "v"(h))

__device__ __forceinline__ u32 pk16(float a, float b) {
  auto p = __builtin_amdgcn_cvt_pkrtz(a, b);   // __fp16x2, same 32-bit layout
  return __builtin_bit_cast(u32, p);
}

__device__ __forceinline__ unsigned short f2bf(float x) {
  uint32_t u = __float_as_uint(x);
  uint32_t r = (u + 0x7fffu + ((u >> 16) & 1u)) >> 16;   // RNE
  return (unsigned short)r;
}

__device__ __forceinline__ float sigf(float x) { return 1.f / (1.f + expf(-x)); }

// ---------------- K_front: gx [0,2560) | zero_seg [2560,5120) | M [5120,5184)
//                  | Wh->f16 pack [5184,5280) ----------------
__global__ __launch_bounds__(256) void k_front(const int* __restrict__ items,
                                               const float* __restrict__ rew,
                                               const float* __restrict__ table,
                                               const float* __restrict__ Wx,
                                               const float* __restrict__ bx,
                                               const float* __restrict__ Wu,
                                               const float* __restrict__ Wi,
                                               const float* __restrict__ Wh,
                                               float* __restrict__ gx,
                                               float* __restrict__ sums,
                                               float* __restrict__ counts,
                                               float* __restrict__ M,
                                               u32* __restrict__ Whf16) {
  __shared__ float Wl[96][140];
  __shared__ float Al[32][128];
  __shared__ float rl[32];
  int bid = blockIdx.x;
  int t = threadIdx.x;
  if (bid < 2560) {
    // ---- gx: Mp=4 x Ng=3 tile ----
    int gt = bid & 3, pt = bid >> 2;
    int g0 = gt * 96, p0 = pt * 32;
    for (int i = t; i < 96 * 34; i += 256) {
      int r = i / 34, c = i % 34;
      f32x4 v = *(const f32x4*)(Wx + (size_t)(g0 + r) * KXX + c * 4);
      *(f32x4*)&Wl[r][c * 4] = v;
    }
    for (int i = t; i < 32 * 32; i += 256) {
      int r = i >> 5, c = i & 31;
      int it = items[p0 + r];
      *(f32x4*)&Al[r][c * 4] = *(const f32x4*)(table + (size_t)it * DD + c * 4);
    }
    if (t < 32) rl[t] = rew[p0 + t];
    __syncthreads();

    int tg = t & 31, pq = t >> 5;
    float acc[4][3] = {};
    for (int k4 = 0; k4 < 32; ++k4) {
      f32x4 a[4];
#pragma unroll
      for (int i = 0; i < 4; ++i) a[i] = *(f32x4*)&Al[pq + 8 * i][k4 * 4];
#pragma unroll
      for (int u = 0; u < 3; ++u) {
        f32x4 w = *(f32x4*)&Wl[tg + 32 * u][k4 * 4];
#pragma unroll
        for (int i = 0; i < 4; ++i)
          acc[i][u] += a[i].x * w.x + a[i].y * w.y + a[i].z * w.z + a[i].w * w.w;
      }
    }
#pragma unroll
    for (int u = 0; u < 3; ++u) {
      int gl = tg + 32 * u, g = g0 + gl;
      float wxr = 0.f;
#pragma unroll
      for (int q = 0; q < 8; ++q) wxr += Wl[gl][128 + q];
      float bxv = bx[g];
#pragma unroll
      for (int i = 0; i < 4; ++i) {
        int p = p0 + pq + 8 * i;
        gx[(size_t)p * G3 + g] = acc[i][u] + rl[pq + 8 * i] * wxr + bxv;
      }
    }
  } else if (bid < 5120) {
    // ---- zero touched sums/counts ----
    int id = (bid - 2560) * 256 + t;
    int p = id >> 5, c = id & 31;
    int it = items[p];
    f32x4 z = {0.f, 0.f, 0.f, 0.f};
    *(f32x4*)(sums + (size_t)it * DD + c * 4) = z;
    if (c == 0) counts[it] = 0.f;
  } else if (bid < 5184) {
    // ---- M = W_u @ W_i^T ----
    int idx = (bid - 5120) * 256 + t;
    int k1 = idx >> 7, k2 = idx & 127;
    float acc = 0.f;
    for (int e = 0; e < DD; ++e)
      acc = fmaf(Wu[k1 * DD + e], Wi[k2 * DD + e], acc);
    M[idx] = acc;
  } else {
    // ---- Wh -> packed f16 pairs ----
    int idx = (bid - 5184) * 256 + t;       // 24576 total
    int g = idx >> 6, c2 = idx & 63;
    const float* src = Wh + (size_t)g * DD + c2 * 2;
    Whf16[idx] = pk16(src[0], src[1]);
  }
}

// ---------------- K_gru: 2 rows/block, wreg from pre-packed Whf16,
//   v_dot2 phase-1, gx PREFETCH rotated one step ahead (hides XCD-miss
//   latency under a full step), LDS hist + deferred tail atomics ----------
__global__ __launch_bounds__(256, 2) void k_gru(const float* __restrict__ gx,
                                                const u32* __restrict__ Whf16,
                                                const float* __restrict__ bh,
                                                const int* __restrict__ items,
                                                float* __restrict__ sums,
                                                float* __restrict__ counts,
                                                float* __restrict__ hT) {
  __shared__ u32   hlu[RPB][DD / 2];     // h per row, packed f16 pairs
  __shared__ float ghl[RPB][G3];         // Wh @ h per row, f32
  __shared__ float hist[RPB][SS][DD];    // 20.5 KB
  __shared__ int   itl[RPB][SS];
  int t = threadIdx.x;
  int gbase = t >> 1, half = t & 1;      // phase-1 identity

  // wreg: 3 slices x 32 packed pairs = 96 u32 VGPRs, contiguous 128 B loads
  u32 wreg[3][32];
#pragma unroll
  for (int tt = 0; tt < 3; ++tt) {
    const u32* src = Whf16 + (size_t)(tt * 128 + gbase) * (DD / 2) + half * 32;
#pragma unroll
    for (int q4 = 0; q4 < 8; ++q4)
      *(u32x4*)&wreg[tt][q4 * 4] = *(const u32x4*)(src + q4 * 4);
  }

  int u2 = t >> 7, w2 = t & 127;         // phase-2 identity: row, d-element
  float bh3[3];
#pragma unroll
  for (int q = 0; q < 3; ++q) bh3[q] = bh[q * 128 + w2];

  int b0 = blockIdx.x * RPB;
  if (t < RPB * SS) itl[t / SS][t % SS] = items[(b0 + t / SS) * SS + t % SS];
  if (t < RPB * (DD / 2)) hlu[t >> 6][t & 63] = 0u;
  const float* gxb = gx + (size_t)(b0 + u2) * SS * G3;
  float hcur = 0.f;
  // prefetch step 0's gx before the loop
  float g3[3];
#pragma unroll
  for (int q = 0; q < 3; ++q) g3[q] = gxb[q * 128 + w2];
  __syncthreads();

  for (int s = 0; s < SS; ++s) {
    // issue step s+1's gx loads NOW; consumed only after the next barrier,
    // so a full step (~700 cyc) of dot2+barriers covers the miss latency
    float g3n[3] = {0.f, 0.f, 0.f};
    if (s + 1 < SS) {
#pragma unroll
      for (int q = 0; q < 3; ++q) g3n[q] = gxb[(s + 1) * G3 + q * 128 + w2];
    }

    // phase 1: 192 dot2 per thread (6 independent chains), 16 b128 LDS reads
#pragma unroll
    for (int r = 0; r < RPB; ++r) {
      float a0 = 0.f, a1 = 0.f, a2 = 0.f;
#pragma unroll
      for (int q4 = 0; q4 < 8; ++q4) {
        u32x4 hv = *(u32x4*)&hlu[r][half * 32 + q4 * 4];
#pragma unroll
        for (int e = 0; e < 4; ++e) {
          u32 h2 = hv[e];
          int j = q4 * 4 + e;
          DOT2(a0, wreg[0][j], h2);
          DOT2(a1, wreg[1][j], h2);
          DOT2(a2, wreg[2][j], h2);
        }
      }
      a0 += __shfl_xor(a0, 1);
      a1 += __shfl_xor(a1, 1);
      a2 += __shfl_xor(a2, 1);
      if (!half) {
        ghl[r][gbase]       = a0;
        ghl[r][128 + gbase] = a1;
        ghl[r][256 + gbase] = a2;
      }
    }
    __syncthreads();
    // phase 2: thread (u2, w2) gate update, f32 (uses current g3)
    float rr = sigf(g3[0] + ghl[u2][w2]       + bh3[0]);
    float zz = sigf(g3[1] + ghl[u2][128 + w2] + bh3[1]);
    float nn = tanhf(g3[2] + rr * (ghl[u2][256 + w2] + bh3[2]));
    hcur = (1.f - zz) * nn + zz * hcur;
    ((_Float16*)&hlu[u2][0])[w2] = (_Float16)hcur;
    hist[u2][s][w2] = hcur;
#pragma unroll
    for (int q = 0; q < 3; ++q) g3[q] = g3n[q];
    __syncthreads();
  }
  hT[(b0 + u2) * DD + w2] = hcur;
  // deferred segment atomics, single drain at exit
  for (int idx = t; idx < RPB * SS * DD; idx += 256) {
    int r = idx / (SS * DD), rem = idx % (SS * DD);
    int s = rem / DD, d = rem % DD;
    atomicAdd(sums + (size_t)itl[r][s] * DD + d, hist[r][s][d]);
  }
  if (t < RPB * SS) atomicAdd(counts + itl[t / SS][t % SS], 1.f);
}

// ---------------- K_back: items [0,12500) | uprime [12500,12564) ----------------
__global__ __launch_bounds__(256) void k_back(const float* __restrict__ table,
                                              const float* __restrict__ mem,
                                              const float* __restrict__ sums,
                                              const float* __restrict__ counts,
                                              unsigned short* __restrict__ Ibf,
                                              const int* __restrict__ ids,
                                              const float* __restrict__ hT,
                                              const float* __restrict__ M,
                                              unsigned short* __restrict__ Ubf) {
  __shared__ int   idsl[BB];
  __shared__ int   repl[16][16];
  __shared__ float hTl[16][DD];
  int bid = blockIdx.x;
  int t = threadIdx.x;
  if (bid < 12500) {
    size_t tid = (size_t)bid * 256 + t;
    size_t i = tid >> 5; int c = (int)(tid & 31);
    if (i >= NII) return;
    float cnt = counts[i];
    size_t base = i * DD + c * 4;
    f32x4 m  = *(const f32x4*)(mem + base);
    f32x4 tb = *(const f32x4*)(table + base);
    float vx, vy, vz, vw;
    if (cnt > 0.f) {
      f32x4 sm = *(const f32x4*)(sums + base);
      vx = 0.5f * (m.x + sm.x / cnt) + tb.x;
      vy = 0.5f * (m.y + sm.y / cnt) + tb.y;
      vz = 0.5f * (m.z + sm.z / cnt) + tb.z;
      vw = 0.5f * (m.w + sm.w / cnt) + tb.w;
    } else {
      vx = m.x + tb.x; vy = m.y + tb.y; vz = m.z + tb.z; vw = m.w + tb.w;
    }
    unsigned long long pack = (unsigned long long)f2bf(vx)
                            | ((unsigned long long)f2bf(vy) << 16)
                            | ((unsigned long long)f2bf(vz) << 32)
                            | ((unsigned long long)f2bf(vw) << 48);
    *(unsigned long long*)(Ibf + base) = pack;
  } else {
    int ub = bid - 12500;
    for (int i = t; i < BB; i += 256) idsl[i] = ids[i];
    __syncthreads();
    int b0 = ub * 16;
    int p = t >> 4, c = t & 15;
    int myid = idsl[b0 + p];
    int best = -1;
    for (int j = c * 64; j < c * 64 + 64; ++j)
      if (idsl[j] == myid) best = j;
    repl[p][c] = best;
    __syncthreads();
    if (c == 0) {
      int rr = -1;
#pragma unroll
      for (int q = 0; q < 16; ++q) rr = max(rr, repl[p][q]);
      repl[p][0] = rr;
    }
    __syncthreads();
    for (int i = t; i < 16 * 32; i += 256) {
      int rr = i >> 5, c4 = i & 31;
      int src = repl[rr][0];
      *(f32x4*)&hTl[rr][c4 * 4] = *(const f32x4*)(hT + (size_t)src * DD + c4 * 4);
    }
    __syncthreads();
    float acc[8] = {0.f, 0.f, 0.f, 0.f, 0.f, 0.f, 0.f, 0.f};
    for (int k1 = 0; k1 < DD; ++k1) {
      float hv = hTl[p][k1];
#pragma unroll
      for (int u = 0; u < 8; ++u)
        acc[u] = fmaf(hv, M[k1 * DD + c + 16 * u], acc[u]);
    }
#pragma unroll
    for (int u = 0; u < 8; ++u)
      Ubf[(size_t)(b0 + p) * DD + c + 16 * u] = f2bf(acc[u]);
  }
}

// ---------------- K_gemm: swapped MFMA, 256-wide j tile, LDS-staged epilogue
//   (one wave stores one ROW = 1024 B contiguous burst) -- round-10 WIN kernel ----
__device__ __forceinline__ bf16x8 bzero8() {
  bf16x8 z;
#pragma unroll
  for (int e = 0; e < 8; ++e) z[e] = (__bf16)0.f;
  return z;
}

__global__ __launch_bounds__(256, 2) void k_gemm(const unsigned short* __restrict__ Ubf,
                                                 const unsigned short* __restrict__ Ibf,
                                                 float* __restrict__ out) {
  __shared__ float ldsT[64][JPB + 4];   // pad 4: +1 bank rotation per b-row
  int j0 = blockIdx.x * JPB;
  int t = threadIdx.x;
  int wv = t >> 6, l = t & 63;
  int jw = j0 + wv * 64;                // wave owns a 64-wide j window
  int lr = l & 15, lk = l >> 4;

  bf16x8 afrag[4][4];
#pragma unroll
  for (int ji = 0; ji < 4; ++ji) {
    int ja = jw + ji * 16 + lr;
#pragma unroll
    for (int kk = 0; kk < 4; ++kk) {
      int k0 = kk * 32 + lk * 8;
      afrag[ji][kk] = (ja < NII) ? *(const bf16x8*)(Ibf + (size_t)ja * DD + k0) : bzero8();
    }
  }
  int jcl = l * 4;
  bool svalid = (j0 + jcl + 4 <= NII);   // NII % 4 == 0

  for (int bc = 0; bc < 16; ++bc) {
    int bw = bc * 64;
    f32x4 acc[4][4];                     // [ji][bi]
#pragma unroll
    for (int ji = 0; ji < 4; ++ji)
#pragma unroll
      for (int bi = 0; bi < 4; ++bi) { f32x4 z = {0.f,0.f,0.f,0.f}; acc[ji][bi] = z; }

#pragma unroll
    for (int kk = 0; kk < 4; ++kk) {
      int k0 = kk * 32 + lk * 8;
#pragma unroll
      for (int bi = 0; bi < 4; ++bi) {
        bf16x8 bfr = *(const bf16x8*)(Ubf + (size_t)(bw + bi * 16 + lr) * DD + k0);
#pragma unroll
        for (int ji = 0; ji < 4; ++ji)
          acc[ji][bi] = __builtin_amdgcn_mfma_f32_16x16x32_bf16(afrag[ji][kk], bfr,
                                                                acc[ji][bi], 0, 0, 0);
      }
    }
    __syncthreads();
#pragma unroll
    for (int ji = 0; ji < 4; ++ji) {
      int jl = wv * 64 + ji * 16 + lk * 4;
#pragma unroll
      for (int bi = 0; bi < 4; ++bi)
        *(f32x4*)&ldsT[bi * 16 + lr][jl] = acc[ji][bi];
    }
    __syncthreads();
    if (svalid) {
#pragma unroll
      for (int rr = 0; rr < 16; ++rr) {
        int row = rr * 4 + wv;
        f32x4 v = *(f32x4*)&ldsT[row][jcl];
        *(f32x4*)(out + (size_t)(bw + row) * NII + j0 + jcl) = v;
      }
    }
  }
}

extern "C" void kernel_launch(void* const* d_in, const int* in_sizes, int n_in,
                              void* d_out, int out_size, void* d_ws, size_t ws_size,
                              hipStream_t stream) {
  const int*   users_ids   = (const int*)  d_in[0];
  const int*   users_items = (const int*)  d_in[1];
  const float* users_rew   = (const float*)d_in[2];
  const float* items_table = (const float*)d_in[4];
  const float* items_mem   = (const float*)d_in[6];
  const float* Wx  = (const float*)d_in[7];
  const float* Wh  = (const float*)d_in[8];
  const float* bx  = (const float*)d_in[9];
  const float* bh  = (const float*)d_in[10];
  const float* W_u = (const float*)d_in[11];
  const float* W_i = (const float*)d_in[12];
  float* out = (float*)d_out;
  (void)in_sizes; (void)n_in; (void)out_size; (void)ws_size;

  char* ws = (char*)d_ws;
  size_t off = 0;
  auto alloc = [&](size_t bytes) {
    void* p = ws + off;
    off = (off + bytes + 255) & ~(size_t)255;
    return p;
  };
  float* sums   = (float*)alloc(sizeof(float) * (size_t)NII * DD);
  float* counts = (float*)alloc(sizeof(float) * NII);
  float* gx     = (float*)alloc(sizeof(float) * (size_t)BB * SS * G3);
  float* M      = (float*)alloc(sizeof(float) * DD * DD);
  float* hT     = (float*)alloc(sizeof(float) * BB * DD);
  u32*   Whf16  = (u32*)alloc(sizeof(u32) * G3 * (DD / 2));
  unsigned short* Ubf = (unsigned short*)alloc(sizeof(unsigned short) * BB * DD);
  unsigned short* Ibf = (unsigned short*)alloc(sizeof(unsigned short) * (size_t)NII * DD);

  hipLaunchKernelGGL(k_front, dim3(5280), dim3(256), 0, stream,
                     users_items, users_rew, items_table, Wx, bx, W_u, W_i, Wh,
                     gx, sums, counts, M, Whf16);
  hipLaunchKernelGGL(k_gru, dim3(BB / RPB), dim3(256), 0, stream,
                     gx, Whf16, bh, users_items, sums, counts, hT);
  hipLaunchKernelGGL(k_back, dim3(12564), dim3(256), 0, stream,
                     items_table, items_mem, sums, counts, Ibf,
                     users_ids, hT, M, Ubf);
  hipLaunchKernelGGL(k_gemm, dim3((NII + JPB - 1) / JPB), dim3(256), 0, stream,
                     Ubf, Ibf, out);
}